// Round 2
// baseline (33152.820 us; speedup 1.0000x reference)
//
#include <hip/hip_runtime.h>
#include <math.h>

// ESN recurrence, persistent kernel, round 5.
// r4 post-mortem: (a) VGPR_Count=104 < 144 -> wreg went to AGPRs, every FMA
// pays a v_accvgpr_read (~2.3k extra cyc/step/SIMD). (b) BANK_CONFLICT
// 232M: part[256][36] reduce-read is 16-way conflicted (row stride 144B,
// reader lanes differ by 2304B = 0 mod 128). (c) occupancy 20% -> LLC/HBM
// latency poorly hidden.
// r5: NTHR=768 (3 waves/SIMD), K split 48 ways (CH=24) -> W/thread = 96
// floats, forced into arch VGPRs by __launch_bounds__(768,1). hx uses a
// chunk-padded layout (28 floats per 24-float chunk) so CH=24 k-loop reads
// stay 2-way/free. part is column-major [48][257] with column permute
// c = kidx ^ 5*th_i: reads conflict-free, writes <=4-way. x_t prefetched
// one step ahead into regs (issued during poll). out-store moved after the
// vmcnt(0) drain. Raw s_barrier + targeted waitcnt replaces __syncthreads
// inside the step (skips re-draining out-stores).

#define T_STEPS 1000
#define NB      64
#define NI      80
#define NH      1024
#define KCAT    (NH + NI)        // 1104
#define NCH     48               // K chunks
#define CH      24               // floats per chunk (K padded to 1152)
#define CH4     (CH / 4)         // 6 float4 per chunk
#define CSTR    28               // padded chunk stride in hx (floats)
#define LSTR    (NCH * CSTR + 4) // 1348 floats per hx row
#define PSTR    257              // part column stride (floats)
#define NGROUPS 4
#define BTILE   16
#define HTILE   16
#define NTHR    768
#define LDS_FLOATS (BTILE * LSTR + NCH * PSTR)   // 21568 + 12336 = 33904
#define LDS_BYTES  (LDS_FLOATS * 4)              // 135,616 B

typedef unsigned long long ull;

__global__ __launch_bounds__(NTHR, 1) void esn_persistent(
    const float* __restrict__ x,        // [T,B,I]
    const int*   __restrict__ lengths,  // [B] descending
    const float* __restrict__ W_ih,     // [H,I]
    const float* __restrict__ W_hh,     // [H,H]
    float* __restrict__ out,            // [T,B,H]
    float*       h_buf,                 // ws: [2][B][H], zero-inited
    unsigned*    flags)                 // ws: [NGROUPS*64], zero-inited
{
    extern __shared__ float lds[];
    float* hx   = lds;                  // [BTILE][LSTR] chunk-padded [h|x|0]
    float* part = lds + BTILE * LSTR;   // [48][PSTR] column-major partials

    const int tid   = threadIdx.x;
    const int bid   = blockIdx.x;
    const int g     = bid >> 6;
    const int htile = bid & 63;
    const int hi0   = htile * HTILE;
    const int gb0   = g * BTILE;

    const int kidx = tid >> 4;          // 0..47 K-chunk
    const int th_i = (tid >> 2) & 3;    // H sub-tile (4 rows)
    const int th_j = tid & 3;           // B sub-tile (4 batches)

    const int max_len = lengths[gb0];   // block-uniform (descending sort)
    unsigned* gflags = flags + g * 64;

    // ---- reader-thread (tid<256) precompute ----
    int lenr = 0, brow_r = 0, hrow_r = 0, hp_addr = 0;
    if (tid < 256) {
        const int b_local = tid & 15;
        const int h_local = tid >> 4;
        brow_r = gb0 + b_local;
        hrow_r = hi0 + h_local;
        lenr   = lengths[brow_r];
        const unsigned hr = (unsigned)hrow_r;
        hp_addr = b_local * LSTR + (int)(hr / 24u) * CSTR + (int)(hr % 24u);
    }

    // ---- part store base: col = kidx ^ 5*th_i (bijective, stays <48) ----
    const int pbase = (kidx ^ (5 * th_i)) * PSTR + 64 * th_i + 4 * th_j;

    // ---- W fragment -> arch VGPRs: rows hi0+4*th_i..+3, cols kidx*24..+23 ----
    float4 wreg[4][CH4];                // 96 VGPRs
    {
        const int k0 = kidx * CH;
        #pragma unroll
        for (int i = 0; i < 4; ++i) {
            const int hr = hi0 + th_i * 4 + i;
            const float* wh = W_hh + (size_t)hr * NH;
            const float* wi = W_ih + (size_t)hr * NI;
            #pragma unroll
            for (int kk = 0; kk < CH4; ++kk) {
                float v[4];
                #pragma unroll
                for (int c = 0; c < 4; ++c) {
                    const int gk = k0 + kk * 4 + c;
                    float w = 0.f;                  // pad cols [1104,1152) = 0
                    if (gk < NH)        w = wh[gk];
                    else if (gk < KCAT) w = wi[gk - NH];
                    v[c] = w;
                }
                wreg[i][kk] = float4{v[0], v[1], v[2], v[3]};
            }
        }
    }

    // ---- x staging assignment (waves 8-11) + first-step prefetch ----
    const bool xa = (tid >= 512);
    const int  xm = tid - 512;          // 0..255
    int xoff0 = 0, xlds0 = 0, xoff1 = 0, xlds1 = 0;
    float4 xr0 = {0,0,0,0}, xr1 = {0,0,0,0};
    if (xa) {
        {
            const unsigned m = (unsigned)xm;
            const int r  = (int)(m / 20u);
            const int c4 = (int)(m % 20u);
            const unsigned col = 1024u + 4u * (unsigned)c4;
            xoff0 = (gb0 + r) * NI + c4 * 4;
            xlds0 = r * LSTR + (int)(col / 24u) * CSTR + (int)(col % 24u);
        }
        if (xm < 64) {
            const unsigned m = (unsigned)(xm + 256);
            const int r  = (int)(m / 20u);
            const int c4 = (int)(m % 20u);
            const unsigned col = 1024u + 4u * (unsigned)c4;
            xoff1 = (gb0 + r) * NI + c4 * 4;
            xlds1 = r * LSTR + (int)(col / 24u) * CSTR + (int)(col % 24u);
        }
        if (max_len > 0) {
            xr0 = *(const float4*)(x + xoff0);           // t = 0
            if (xm < 64) xr1 = *(const float4*)(x + xoff1);
        }
    }

    // ---- zero LDS once (pad chunks 46/47 + part) ----
    for (int i = tid; i < LDS_FLOATS; i += NTHR) lds[i] = 0.f;
    __syncthreads();

    for (int t = 0; t < max_len; ++t) {
        const float* h_cur = h_buf + (size_t)(t & 1) * (NB * NH);
        float*       h_nxt = h_buf + (size_t)((t + 1) & 1) * (NB * NH);

        // ---- stage: waves 0-7 do h (coherent 8B), waves 8-11 write x regs ----
        if (tid < 512) {
            const ull* h8 = (const ull*)(h_cur + (size_t)gb0 * NH);
            ull vb[16];
            #pragma unroll
            for (int it = 0; it < 16; ++it) {
                const int j = tid + it * 512;           // 0..8191
                vb[it] = __hip_atomic_load(h8 + ((j >> 9) * 512 + (j & 511)),
                           __ATOMIC_RELAXED, __HIP_MEMORY_SCOPE_AGENT);
            }
            #pragma unroll
            for (int it = 0; it < 16; ++it) {
                const int j   = tid + it * 512;
                const int row = j >> 9;
                const unsigned c2 = (unsigned)(j & 511);
                const int addr = row * LSTR + (int)(c2 / 12u) * CSTR
                               + 2 * (int)(c2 % 12u);
                *(ull*)(&hx[addr]) = vb[it];
            }
        } else {
            *(float4*)(&hx[xlds0]) = xr0;
            if (xm < 64) *(float4*)(&hx[xlds1]) = xr1;
        }
        asm volatile("s_waitcnt lgkmcnt(0)" ::: "memory");
        __builtin_amdgcn_s_barrier();
        __builtin_amdgcn_sched_barrier(0);

        // ---- 4H x 4B micro-tile over this thread's 24-col K-chunk ----
        float acc[4][4];
        #pragma unroll
        for (int i = 0; i < 4; ++i)
            #pragma unroll
            for (int j = 0; j < 4; ++j) acc[i][j] = 0.f;

        #pragma unroll
        for (int j = 0; j < 4; ++j) {
            const float* hb = hx + (size_t)(th_j * 4 + j) * LSTR + kidx * CSTR;
            #pragma unroll
            for (int kk = 0; kk < CH4; ++kk) {
                const float4 hv = *(const float4*)(hb + kk * 4);
                #pragma unroll
                for (int i = 0; i < 4; ++i) {
                    acc[i][j] = fmaf(wreg[i][kk].x, hv.x,
                                fmaf(wreg[i][kk].y, hv.y,
                                fmaf(wreg[i][kk].z, hv.z,
                                fmaf(wreg[i][kk].w, hv.w, acc[i][j]))));
                }
            }
        }

        // ---- publish partials: part[c][r], writes <=4-way by permute ----
        #pragma unroll
        for (int i = 0; i < 4; ++i)
            #pragma unroll
            for (int j = 0; j < 4; ++j)
                part[pbase + 16 * i + j] = acc[i][j];
        asm volatile("s_waitcnt lgkmcnt(0)" ::: "memory");
        __builtin_amdgcn_s_barrier();
        __builtin_amdgcn_sched_barrier(0);

        // ---- reduce 48 partials (conflict-free: bank = tid mod 32) ----
        float y = 0.f;
        if (tid < 256) {
            float s0 = 0.f, s1 = 0.f, s2 = 0.f, s3 = 0.f;
            #pragma unroll
            for (int c = 0; c < NCH; c += 4) {
                s0 += part[(c + 0) * PSTR + tid];
                s1 += part[(c + 1) * PSTR + tid];
                s2 += part[(c + 2) * PSTR + tid];
                s3 += part[(c + 3) * PSTR + tid];
            }
            const float accv = (s0 + s1) + (s2 + s3);
            const float hp = hx[hp_addr];
            float hn;
            if (t < lenr) { hn = 0.5f * hp + 0.5f * tanhf(accv); y = hn; }
            else          { hn = hp; /* y stays 0 */ }
            __hip_atomic_store(&h_nxt[(size_t)brow_r * NH + hrow_r], hn,
                               __ATOMIC_RELAXED, __HIP_MEMORY_SCOPE_AGENT);
        }

        // ---- group barrier: drain h-store only, then flag/publish/poll ----
        asm volatile("s_waitcnt vmcnt(0) lgkmcnt(0)" ::: "memory");
        __builtin_amdgcn_s_barrier();
        __builtin_amdgcn_sched_barrier(0);
        if (tid == 0)
            __hip_atomic_store(&gflags[htile], (unsigned)(t + 1),
                               __ATOMIC_RELAXED, __HIP_MEMORY_SCOPE_AGENT);
        if (tid < 256)                       // out-store overlaps the poll
            out[((size_t)t * NB + brow_r) * NH + hrow_r] = y;
        if (xa && (t + 1 < max_len)) {       // prefetch x[t+1] during poll
            const float* xt = x + (size_t)(t + 1) * (NB * NI);
            xr0 = *(const float4*)(xt + xoff0);
            if (xm < 64) xr1 = *(const float4*)(xt + xoff1);
        }
        if (tid < 64) {
            while (__hip_atomic_load(&gflags[tid],
                     __ATOMIC_RELAXED, __HIP_MEMORY_SCOPE_AGENT)
                   < (unsigned)(t + 1))
                __builtin_amdgcn_s_sleep(1);
        }
        __builtin_amdgcn_s_barrier();
        __builtin_amdgcn_sched_barrier(0);
    }

    // ---- tail: whole group past its max length -> zero outputs (float4) ----
    const float4 z4 = {0.f, 0.f, 0.f, 0.f};
    for (int p = tid; p < (T_STEPS - max_len) * 64; p += NTHR) {
        const int t = max_len + (p >> 6);
        const int o = p & 63;                // 16 b x 4 float4
        const int b = o >> 2;
        const int c = o & 3;
        *(float4*)(out + ((size_t)t * NB + gb0 + b) * NH + hi0 + c * 4) = z4;
    }
}

extern "C" void kernel_launch(void* const* d_in, const int* in_sizes, int n_in,
                              void* d_out, int out_size, void* d_ws, size_t ws_size,
                              hipStream_t stream) {
    const float* x       = (const float*)d_in[0];
    const int*   lengths = (const int*)  d_in[1];
    const float* W_ih    = (const float*)d_in[2];
    const float* W_hh    = (const float*)d_in[3];
    float*       out     = (float*)d_out;

    float*    h_buf = (float*)d_ws;                                   // 512 KB
    unsigned* flags = (unsigned*)((char*)d_ws + 2 * NB * NH * sizeof(float));

    hipMemsetAsync(d_ws, 0,
                   2 * NB * NH * sizeof(float) + NGROUPS * 64 * sizeof(unsigned),
                   stream);

    hipFuncSetAttribute((const void*)esn_persistent,
                        hipFuncAttributeMaxDynamicSharedMemorySize, LDS_BYTES);

    esn_persistent<<<dim3(NGROUPS * 64), dim3(NTHR), LDS_BYTES, stream>>>(
        x, lengths, W_ih, W_hh, out, h_buf, flags);
}

// Round 3
// 19786.037 us; speedup vs baseline: 1.6756x; 1.6756x over previous
//
#include <hip/hip_runtime.h>
#include <math.h>

// ESN recurrence, round 6: i2h precompute + W-in-VGPR recurrence at 4 waves/SIMD.
// r5 post-mortem: FETCH 62.5GB = wreg spilled to scratch (165 regs vs 170
// budget); never run the allocator at the edge. r4 re-analysis: with LDS
// broadcast, k-loop LDS was cheap; 16.1k cyc/step was latency exposure at
// 2 waves/SIMD + AGPR copies.
// r6: (1) i2h = x@W_ih^T precomputed by a separate GEMM kernel INTO out
//     (same shape); recurrence reads i2h[t] prefetched during the poll and
//     overwrites with y. K drops to 1024 exactly (64 chunks x 16).
// (2) NTHR=1024 (4 waves/SIMD), micro-tile 4Hx4B, CH=16 -> wreg=64 floats;
//     total ~115 VGPR, well under the 128 hard cap of a 1024-thread block.
// (3) f4-granular XOR swizzle on hx (c4 ^= row>>2): k-loop 8 bank-groups
//     x2-way (free), staging writes contiguous per lane, part writes all-32
//     banks, reduce reads 2-way free.
// (4) r3/r5 proven group-barrier + poll kept.

#define T_STEPS 1000
#define NB      64
#define NI      80
#define NH      1024
#define NCH     64               // K chunks
#define CH      16               // floats per chunk (K = 1024 exact)
#define LSTR    1028             // hx row stride (1024 + 4 pad floats)
#define PSTR    257              // part column stride
#define NGROUPS 4
#define BTILE   16
#define HTILE   16
#define NTHR    1024
#define HX_FLOATS  (BTILE * LSTR)                // 16448
#define LDS_FLOATS (HX_FLOATS + NCH * PSTR)      // 32896
#define LDS_BYTES  (LDS_FLOATS * 4)              // 131584
#define I2H_LDS_BYTES (4 * NB * NI * 4)          // 81920

typedef unsigned long long ull;

// ---------- phase 1: out[t,b,h] = sum_i x[t,b,i] * W_ih[h,i] ----------
__global__ __launch_bounds__(1024, 4) void i2h_gemm(
    const float* __restrict__ x,      // [T,B,I]
    const float* __restrict__ W_ih,   // [H,I]
    float* __restrict__ out)          // [T,B,H]
{
    extern __shared__ float xs[];     // [4][NB][NI] = 20480 floats
    const int tid = threadIdx.x;
    const int t0  = blockIdx.x * 4;

    // stage x[t0..t0+3]: 5120 contiguous float4
    {
        const float4* src = (const float4*)(x + (size_t)t0 * NB * NI);
        float4* dst = (float4*)xs;
        #pragma unroll
        for (int r = 0; r < 5; ++r)
            dst[tid + r * 1024] = src[tid + r * 1024];
    }
    // this thread's W_ih row (h = tid) -> 20 float4 in regs
    float4 w[20];
    {
        const float4* wr = (const float4*)(W_ih + (size_t)tid * NI);
        #pragma unroll
        for (int k = 0; k < 20; ++k) w[k] = wr[k];
    }
    __syncthreads();

    for (int tq = 0; tq < 4; ++tq) {
        for (int jb = 0; jb < 16; ++jb) {
            const float* xb = xs + (size_t)(tq * NB + jb * 4) * NI;
            float a0 = 0.f, a1 = 0.f, a2 = 0.f, a3 = 0.f;
            #pragma unroll
            for (int k = 0; k < 20; ++k) {
                const float4 wv = w[k];
                float4 xv;
                xv = *(const float4*)(xb + k * 4);            // full-wave broadcast
                a0 = fmaf(wv.x, xv.x, fmaf(wv.y, xv.y,
                     fmaf(wv.z, xv.z, fmaf(wv.w, xv.w, a0))));
                xv = *(const float4*)(xb + NI + k * 4);
                a1 = fmaf(wv.x, xv.x, fmaf(wv.y, xv.y,
                     fmaf(wv.z, xv.z, fmaf(wv.w, xv.w, a1))));
                xv = *(const float4*)(xb + 2 * NI + k * 4);
                a2 = fmaf(wv.x, xv.x, fmaf(wv.y, xv.y,
                     fmaf(wv.z, xv.z, fmaf(wv.w, xv.w, a2))));
                xv = *(const float4*)(xb + 3 * NI + k * 4);
                a3 = fmaf(wv.x, xv.x, fmaf(wv.y, xv.y,
                     fmaf(wv.z, xv.z, fmaf(wv.w, xv.w, a3))));
            }
            float* ob = out + ((size_t)(t0 + tq) * NB + jb * 4) * NH + tid;
            ob[0]      = a0;                                  // coalesced: h = tid
            ob[NH]     = a1;
            ob[2 * NH] = a2;
            ob[3 * NH] = a3;
        }
    }
}

// ---------- phase 2: persistent recurrence ----------
__global__ __launch_bounds__(NTHR, 4) void esn_persistent(
    const int*   __restrict__ lengths,  // [B] descending
    const float* __restrict__ W_hh,     // [H,H]
    float* __restrict__ out,            // [T,B,H], holds i2h on entry
    float*       h_buf,                 // ws: [2][B][H], zero-inited
    unsigned*    flags)                 // ws: [NGROUPS*64], zero-inited
{
    extern __shared__ float lds[];
    float* hx   = lds;                  // [BTILE][LSTR], f4-XOR-swizzled
    float* part = lds + HX_FLOATS;      // [NCH][PSTR] column-major partials

    const int tid   = threadIdx.x;
    const int bid   = blockIdx.x;
    const int g     = bid >> 6;
    const int htile = bid & 63;
    const int hi0   = htile * HTILE;
    const int gb0   = g * BTILE;

    const int kidx = tid >> 4;          // 0..63 K-chunk (4 consecutive per wave)
    const int th_i = (tid >> 2) & 3;    // H sub-tile (4 rows)
    const int th_j = tid & 3;           // B sub-tile (4 batch rows)

    const int max_len = lengths[gb0];   // block-uniform (descending sort)
    unsigned* gflags = flags + g * 64;

    // ---- reader-thread (tid<256) precompute ----
    int lenr = 0, brow_r = 0, hrow_r = 0, hp_addr = 0;
    if (tid < 256) {
        const int b_local = tid >> 4;
        const int h_local = tid & 15;
        brow_r = gb0 + b_local;
        hrow_r = hi0 + h_local;
        lenr   = lengths[brow_r];
        const int c4 = hrow_r >> 2;
        hp_addr = b_local * LSTR + ((c4 ^ ((b_local >> 2) & 3)) << 2)
                + (hrow_r & 3);
    }

    // part write base: col = kidx, row r = b_local*16 + h_local
    // per-inst banks = kidx(4) + 4*th_i(4) + 16*(th_j&1)(2) -> all 32, free
    const int pbase = kidx * PSTR;

    // ---- W fragment -> VGPRs: rows hi0+4*th_i+i, f4-cols kidx*4+kk ----
    float4 wreg[4][4];                  // 64 VGPRs
    #pragma unroll
    for (int i = 0; i < 4; ++i) {
        const float4* wr =
            (const float4*)(W_hh + (size_t)(hi0 + th_i * 4 + i) * NH) + kidx * 4;
        #pragma unroll
        for (int kk = 0; kk < 4; ++kk) wreg[i][kk] = wr[kk];
    }

    // ---- i2h prefetch (step 0) ----
    float i2h_c = 0.f;
    if (tid < 256 && max_len > 0)
        i2h_c = out[((size_t)0 * NB + brow_r) * NH + hrow_r];

    __syncthreads();

    for (int t = 0; t < max_len; ++t) {
        const float* h_cur = h_buf + (size_t)(t & 1) * (NB * NH);
        float*       h_nxt = h_buf + (size_t)((t + 1) & 1) * (NB * NH);

        // ---- stage h: 8 coherent 8B loads/thread, then swizzled LDS writes ----
        {
            const ull* h8 = (const ull*)(h_cur + (size_t)gb0 * NH);
            ull vb[8];
            #pragma unroll
            for (int it = 0; it < 8; ++it)
                vb[it] = __hip_atomic_load(h8 + (tid + it * NTHR),
                           __ATOMIC_RELAXED, __HIP_MEMORY_SCOPE_AGENT);
            #pragma unroll
            for (int it = 0; it < 8; ++it) {
                const int j   = tid + it * NTHR;
                const int row = j >> 9;               // 0..15
                const int c2  = j & 511;              // ull col
                const int c4  = c2 >> 1;
                const int ad  = row * LSTR
                              + (((c4 ^ ((row >> 2) & 3))) << 2)
                              + ((c2 & 1) << 1);
                *(ull*)(&hx[ad]) = vb[it];
            }
        }
        asm volatile("s_waitcnt lgkmcnt(0)" ::: "memory");
        __builtin_amdgcn_s_barrier();
        __builtin_amdgcn_sched_barrier(0);

        // ---- 4H x 4B micro-tile over this thread's 16-col K-chunk ----
        float acc[4][4];
        #pragma unroll
        for (int i = 0; i < 4; ++i)
            #pragma unroll
            for (int j = 0; j < 4; ++j) acc[i][j] = 0.f;

        #pragma unroll
        for (int j = 0; j < 4; ++j) {
            const float* hb = hx + (size_t)(4 * th_j + j) * LSTR;
            #pragma unroll
            for (int kk = 0; kk < 4; ++kk) {
                const int c4 = (kidx * 4 + kk) ^ th_j;   // involution w/ staging
                const float4 hv = *(const float4*)(hb + (c4 << 2));
                #pragma unroll
                for (int i = 0; i < 4; ++i) {
                    acc[i][j] = fmaf(wreg[i][kk].x, hv.x,
                                fmaf(wreg[i][kk].y, hv.y,
                                fmaf(wreg[i][kk].z, hv.z,
                                fmaf(wreg[i][kk].w, hv.w, acc[i][j]))));
                }
            }
        }

        // ---- publish partials: part[kidx][(4*th_j+j)*16 + 4*th_i+i] ----
        #pragma unroll
        for (int i = 0; i < 4; ++i)
            #pragma unroll
            for (int j = 0; j < 4; ++j)
                part[pbase + (4 * th_j + j) * 16 + 4 * th_i + i] = acc[i][j];
        asm volatile("s_waitcnt lgkmcnt(0)" ::: "memory");
        __builtin_amdgcn_s_barrier();
        __builtin_amdgcn_sched_barrier(0);

        // ---- reduce 64 partials (banks = c + tid mod 32: 2-way, free) ----
        float y = 0.f;
        if (tid < 256) {
            float s0 = 0.f, s1 = 0.f, s2 = 0.f, s3 = 0.f;
            #pragma unroll
            for (int c = 0; c < NCH; c += 4) {
                s0 += part[(c + 0) * PSTR + tid];
                s1 += part[(c + 1) * PSTR + tid];
                s2 += part[(c + 2) * PSTR + tid];
                s3 += part[(c + 3) * PSTR + tid];
            }
            const float accv = ((s0 + s1) + (s2 + s3)) + i2h_c;
            const float hp = hx[hp_addr];
            float hn;
            if (t < lenr) { hn = 0.5f * hp + 0.5f * tanhf(accv); y = hn; }
            else          { hn = hp; /* y stays 0 */ }
            __hip_atomic_store(&h_nxt[(size_t)brow_r * NH + hrow_r], hn,
                               __ATOMIC_RELAXED, __HIP_MEMORY_SCOPE_AGENT);
        }

        // ---- group barrier: drain h-store, flag, overlap out-store + ----
        // ---- i2h prefetch with the poll                                ----
        asm volatile("s_waitcnt vmcnt(0) lgkmcnt(0)" ::: "memory");
        __builtin_amdgcn_s_barrier();
        __builtin_amdgcn_sched_barrier(0);
        if (tid == 0)
            __hip_atomic_store(&gflags[htile], (unsigned)(t + 1),
                               __ATOMIC_RELAXED, __HIP_MEMORY_SCOPE_AGENT);
        if (tid < 256) {
            out[((size_t)t * NB + brow_r) * NH + hrow_r] = y;
            if (t + 1 < max_len)
                i2h_c = out[((size_t)(t + 1) * NB + brow_r) * NH + hrow_r];
        }
        if (tid < 64) {
            while (__hip_atomic_load(&gflags[tid],
                     __ATOMIC_RELAXED, __HIP_MEMORY_SCOPE_AGENT)
                   < (unsigned)(t + 1))
                __builtin_amdgcn_s_sleep(1);
        }
        __builtin_amdgcn_s_barrier();
        __builtin_amdgcn_sched_barrier(0);
    }

    // ---- tail: whole group past its max length -> zero outputs ----
    const float4 z4 = {0.f, 0.f, 0.f, 0.f};
    for (int p = tid; p < (T_STEPS - max_len) * 64; p += NTHR) {
        const int t = max_len + (p >> 6);
        const int o = p & 63;                // 16 b x 4 float4
        const int b = o >> 2;
        const int c = o & 3;
        *(float4*)(out + ((size_t)t * NB + gb0 + b) * NH + hi0 + c * 4) = z4;
    }
}

extern "C" void kernel_launch(void* const* d_in, const int* in_sizes, int n_in,
                              void* d_out, int out_size, void* d_ws, size_t ws_size,
                              hipStream_t stream) {
    const float* x       = (const float*)d_in[0];
    const int*   lengths = (const int*)  d_in[1];
    const float* W_ih    = (const float*)d_in[2];
    const float* W_hh    = (const float*)d_in[3];
    float*       out     = (float*)d_out;

    float*    h_buf = (float*)d_ws;                                   // 512 KB
    unsigned* flags = (unsigned*)((char*)d_ws + 2 * NB * NH * sizeof(float));

    hipMemsetAsync(d_ws, 0,
                   2 * NB * NH * sizeof(float) + NGROUPS * 64 * sizeof(unsigned),
                   stream);

    hipFuncSetAttribute((const void*)i2h_gemm,
                        hipFuncAttributeMaxDynamicSharedMemorySize, I2H_LDS_BYTES);
    hipFuncSetAttribute((const void*)esn_persistent,
                        hipFuncAttributeMaxDynamicSharedMemorySize, LDS_BYTES);

    // phase 1: i2h into out (stream-ordered; visible to phase 2)
    i2h_gemm<<<dim3(T_STEPS / 4), dim3(1024), I2H_LDS_BYTES, stream>>>(
        x, W_ih, out);

    // phase 2: recurrence
    esn_persistent<<<dim3(NGROUPS * 64), dim3(NTHR), LDS_BYTES, stream>>>(
        lengths, W_hh, out, h_buf, flags);
}

// Round 4
// 6175.507 us; speedup vs baseline: 5.3684x; 3.2040x over previous
//
#include <hip/hip_runtime.h>
#include <math.h>

// ESN recurrence, round 7.
// r5/r6 post-mortem: both regressions were W-fragment spill. r5: 165 regs
// vs 170 budget (edge). r6: 1024-thr block (128 budget) + DYNAMIC shared
// memory hides the LDS occupancy cap -> allocator chases phantom occupancy,
// sheds W to scratch (VGPR=64, FETCH 10.2GB, VALUBusy 4.5%).
// r7: back to 512 threads (256-reg budget), demand ~198 (23% headroom);
// amdgpu_waves_per_eu(2,2) pins the codegen occupancy target so the
// allocator stops minimizing regs. Keeps r6's good pieces: i2h precompute
// into `out` (K=1024 exact), W-in-regs, group-flag barrier. Sync reverts to
// r4's proven __syncthreads + s_waitcnt(0).
// Layout: kidx=tid>>4 (32 chunks x 32 floats), tile 4Hx4B -> wreg=128 fl.
// k-loop reads rotated per-thread (rotation folded into W load; register
// indices static per rule #20) -> <=2-way banks. part[32][257] col-major,
// pcol=(kidx+8*th_j)&31 -> writes/reads <=2-way.

#define T_STEPS 1000
#define NB      64
#define NI      80
#define NH      1024
#define NCH     32               // K chunks
#define CH      32               // floats per chunk (K = 1024 exact)
#define LSTR    1028             // hx row stride (1024 + 4 pad floats)
#define PSTR    257              // part column stride
#define NGROUPS 4
#define BTILE   16
#define HTILE   16
#define NTHR    512
#define HX_FLOATS   (BTILE * LSTR)               // 16448
#define PART_FLOATS (NCH * PSTR)                 // 8224
#define LDS_FLOATS  (HX_FLOATS + PART_FLOATS)    // 24672
#define LDS_BYTES   (LDS_FLOATS * 4)             // 98,688 B -> 1 block/CU
#define I2H_LDS_BYTES (4 * NB * NI * 4)          // 81,920 B

typedef unsigned long long ull;

// ---------- phase 1: out[t,b,h] = sum_i x[t,b,i] * W_ih[h,i] ----------
__global__ __launch_bounds__(1024, 4) void i2h_gemm(
    const float* __restrict__ x,      // [T,B,I]
    const float* __restrict__ W_ih,   // [H,I]
    float* __restrict__ out)          // [T,B,H]
{
    extern __shared__ float xs[];     // [4][NB][NI] = 20480 floats
    const int tid = threadIdx.x;
    const int t0  = blockIdx.x * 4;

    {
        const float4* src = (const float4*)(x + (size_t)t0 * NB * NI);
        float4* dst = (float4*)xs;
        #pragma unroll
        for (int r = 0; r < 5; ++r)
            dst[tid + r * 1024] = src[tid + r * 1024];
    }
    float4 w[20];
    {
        const float4* wr = (const float4*)(W_ih + (size_t)tid * NI);
        #pragma unroll
        for (int k = 0; k < 20; ++k) w[k] = wr[k];
    }
    __syncthreads();

    for (int tq = 0; tq < 4; ++tq) {
        for (int jb = 0; jb < 16; ++jb) {
            const float* xb = xs + (size_t)(tq * NB + jb * 4) * NI;
            float a0 = 0.f, a1 = 0.f, a2 = 0.f, a3 = 0.f;
            #pragma unroll
            for (int k = 0; k < 20; ++k) {
                const float4 wv = w[k];
                float4 xv;
                xv = *(const float4*)(xb + k * 4);
                a0 = fmaf(wv.x, xv.x, fmaf(wv.y, xv.y,
                     fmaf(wv.z, xv.z, fmaf(wv.w, xv.w, a0))));
                xv = *(const float4*)(xb + NI + k * 4);
                a1 = fmaf(wv.x, xv.x, fmaf(wv.y, xv.y,
                     fmaf(wv.z, xv.z, fmaf(wv.w, xv.w, a1))));
                xv = *(const float4*)(xb + 2 * NI + k * 4);
                a2 = fmaf(wv.x, xv.x, fmaf(wv.y, xv.y,
                     fmaf(wv.z, xv.z, fmaf(wv.w, xv.w, a2))));
                xv = *(const float4*)(xb + 3 * NI + k * 4);
                a3 = fmaf(wv.x, xv.x, fmaf(wv.y, xv.y,
                     fmaf(wv.z, xv.z, fmaf(wv.w, xv.w, a3))));
            }
            float* ob = out + ((size_t)(t0 + tq) * NB + jb * 4) * NH + tid;
            ob[0]      = a0;
            ob[NH]     = a1;
            ob[2 * NH] = a2;
            ob[3 * NH] = a3;
        }
    }
}

// ---------- phase 2: persistent recurrence ----------
__attribute__((amdgpu_waves_per_eu(2, 2)))
__global__ void __launch_bounds__(NTHR) esn_persistent(
    const int*   __restrict__ lengths,  // [B] descending
    const float* __restrict__ W_hh,     // [H,H]
    float* __restrict__ out,            // [T,B,H], holds i2h on entry
    float*       h_buf,                 // ws: [2][B][H], zero-inited
    unsigned*    flags)                 // ws: [NGROUPS*64], zero-inited
{
    extern __shared__ float lds[];
    float* hx   = lds;                  // [BTILE][LSTR], plain layout
    float* part = lds + HX_FLOATS;      // [NCH][PSTR] column-major partials

    const int tid   = threadIdx.x;
    const int bid   = blockIdx.x;
    const int g     = bid >> 6;
    const int htile = bid & 63;
    const int hi0   = htile * HTILE;
    const int gb0   = g * BTILE;

    const int kidx = tid >> 4;          // 0..31 K-chunk
    const int th_i = (tid >> 2) & 3;    // H sub-tile (4 rows)
    const int th_j = tid & 3;           // B sub-tile (4 batch rows)

    const int max_len = lengths[gb0];   // block-uniform (descending sort)
    unsigned* gflags = flags + g * 64;

    // ---- reader-thread (tid<256) precompute ----
    int lenr = 0, brow_r = 0, hrow_r = 0, hp_addr = 0;
    if (tid < 256) {
        const int b_local = tid >> 4;
        const int h_local = tid & 15;
        brow_r = gb0 + b_local;
        hrow_r = hi0 + h_local;
        lenr   = lengths[brow_r];
        hp_addr = b_local * LSTR + hrow_r;
    }

    // ---- rotated chunk offsets (float offsets within an hx row) ----
    // rotation spreads the 4 kidx of a wave over distinct bank groups;
    // folded into the W load so all register indices stay compile-time.
    const int rot = kidx & 3;
    int off[8];
    #pragma unroll
    for (int kk = 0; kk < 8; ++kk)
        off[kk] = (kidx * 8 + ((kk + rot) & 7)) * 4;

    // ---- W fragment -> VGPRs: rows hi0+4*th_i+i, rotated f4 columns ----
    float4 wreg[4][8];                  // 128 VGPRs
    #pragma unroll
    for (int i = 0; i < 4; ++i) {
        const float* wr = W_hh + (size_t)(hi0 + th_i * 4 + i) * NH;
        #pragma unroll
        for (int kk = 0; kk < 8; ++kk)
            wreg[i][kk] = *(const float4*)(wr + off[kk]);
    }

    // part column: bijective in kidx for fixed th_j; spreads banks
    const int pcol = (kidx + 8 * th_j) & 31;

    // ---- i2h prefetch (step 0) ----
    float i2h_c = 0.f;
    if (tid < 256 && max_len > 0)
        i2h_c = out[(size_t)brow_r * NH + hrow_r];

    for (int t = 0; t < max_len; ++t) {
        const float* h_cur = h_buf + (size_t)(t & 1) * (NB * NH);
        float*       h_nxt = h_buf + (size_t)((t + 1) & 1) * (NB * NH);

        // ---- stage h: 2 rounds x 8 coherent 8B loads, then LDS writes ----
        {
            const ull* h8 = (const ull*)(h_cur + (size_t)gb0 * NH);
            ull vb[8];
            #pragma unroll
            for (int it = 0; it < 8; ++it)
                vb[it] = __hip_atomic_load(h8 + (tid + it * NTHR),
                           __ATOMIC_RELAXED, __HIP_MEMORY_SCOPE_AGENT);
            #pragma unroll
            for (int it = 0; it < 8; ++it) {
                const int j = tid + it * NTHR;
                *(ull*)(&hx[(j >> 9) * LSTR + (j & 511) * 2]) = vb[it];
            }
            #pragma unroll
            for (int it = 0; it < 8; ++it)
                vb[it] = __hip_atomic_load(h8 + (tid + (it + 8) * NTHR),
                           __ATOMIC_RELAXED, __HIP_MEMORY_SCOPE_AGENT);
            #pragma unroll
            for (int it = 0; it < 8; ++it) {
                const int j = tid + (it + 8) * NTHR;
                *(ull*)(&hx[(j >> 9) * LSTR + (j & 511) * 2]) = vb[it];
            }
        }
        __syncthreads();

        // ---- 4H x 4B micro-tile over this thread's 32-col K-chunk ----
        float acc[4][4];
        #pragma unroll
        for (int i = 0; i < 4; ++i)
            #pragma unroll
            for (int j = 0; j < 4; ++j) acc[i][j] = 0.f;

        #pragma unroll
        for (int j = 0; j < 4; ++j) {
            const float* hb = hx + (size_t)(th_j * 4 + j) * LSTR;
            #pragma unroll
            for (int kk = 0; kk < 8; ++kk) {
                const float4 hv = *(const float4*)(hb + off[kk]);
                #pragma unroll
                for (int i = 0; i < 4; ++i) {
                    acc[i][j] = fmaf(wreg[i][kk].x, hv.x,
                                fmaf(wreg[i][kk].y, hv.y,
                                fmaf(wreg[i][kk].z, hv.z,
                                fmaf(wreg[i][kk].w, hv.w, acc[i][j]))));
                }
            }
        }

        // ---- publish partials: part[pcol][(4*th_j+j)*16 + 4*th_i+i] ----
        #pragma unroll
        for (int i = 0; i < 4; ++i)
            #pragma unroll
            for (int j = 0; j < 4; ++j)
                part[pcol * PSTR + (th_j * 4 + j) * 16 + th_i * 4 + i]
                    = acc[i][j];
        __syncthreads();

        // ---- reduce 32 partials (banks = c + tid mod 32: 2-way, free) ----
        float y = 0.f;
        if (tid < 256) {
            float s0 = 0.f, s1 = 0.f, s2 = 0.f, s3 = 0.f;
            #pragma unroll
            for (int c = 0; c < NCH; c += 4) {
                s0 += part[(c + 0) * PSTR + tid];
                s1 += part[(c + 1) * PSTR + tid];
                s2 += part[(c + 2) * PSTR + tid];
                s3 += part[(c + 3) * PSTR + tid];
            }
            const float accv = ((s0 + s1) + (s2 + s3)) + i2h_c;
            const float hp = hx[hp_addr];
            float hn;
            if (t < lenr) { hn = 0.5f * hp + 0.5f * tanhf(accv); y = hn; }
            else          { hn = hp; /* y stays 0 */ }
            __hip_atomic_store(&h_nxt[(size_t)brow_r * NH + hrow_r], hn,
                               __ATOMIC_RELAXED, __HIP_MEMORY_SCOPE_AGENT);
        }

        // ---- group barrier (r4-proven): drain, flag, overlap, poll ----
        __builtin_amdgcn_s_waitcnt(0);   // this wave's stores complete at LLC
        __syncthreads();                 // => all waves' stores complete
        if (tid == 0)
            __hip_atomic_store(&gflags[htile], (unsigned)(t + 1),
                               __ATOMIC_RELAXED, __HIP_MEMORY_SCOPE_AGENT);
        if (tid < 256) {                 // overlap with the poll
            out[((size_t)t * NB + brow_r) * NH + hrow_r] = y;
            if (t + 1 < max_len)
                i2h_c = out[((size_t)(t + 1) * NB + brow_r) * NH + hrow_r];
        }
        if (tid < 64) {
            while (__hip_atomic_load(&gflags[tid],
                     __ATOMIC_RELAXED, __HIP_MEMORY_SCOPE_AGENT)
                   < (unsigned)(t + 1))
                __builtin_amdgcn_s_sleep(1);
        }
        __syncthreads();
    }

    // ---- tail: whole group past its max length -> zero outputs ----
    const float4 z4 = {0.f, 0.f, 0.f, 0.f};
    for (int p = tid; p < (T_STEPS - max_len) * 64; p += NTHR) {
        const int t = max_len + (p >> 6);
        const int o = p & 63;                // 16 b x 4 float4
        const int b = o >> 2;
        const int c = o & 3;
        *(float4*)(out + ((size_t)t * NB + gb0 + b) * NH + hi0 + c * 4) = z4;
    }
}

extern "C" void kernel_launch(void* const* d_in, const int* in_sizes, int n_in,
                              void* d_out, int out_size, void* d_ws, size_t ws_size,
                              hipStream_t stream) {
    const float* x       = (const float*)d_in[0];
    const int*   lengths = (const int*)  d_in[1];
    const float* W_ih    = (const float*)d_in[2];
    const float* W_hh    = (const float*)d_in[3];
    float*       out     = (float*)d_out;

    float*    h_buf = (float*)d_ws;                                   // 512 KB
    unsigned* flags = (unsigned*)((char*)d_ws + 2 * NB * NH * sizeof(float));

    hipMemsetAsync(d_ws, 0,
                   2 * NB * NH * sizeof(float) + NGROUPS * 64 * sizeof(unsigned),
                   stream);

    hipFuncSetAttribute((const void*)i2h_gemm,
                        hipFuncAttributeMaxDynamicSharedMemorySize, I2H_LDS_BYTES);
    hipFuncSetAttribute((const void*)esn_persistent,
                        hipFuncAttributeMaxDynamicSharedMemorySize, LDS_BYTES);

    // phase 1: i2h into out (stream-ordered; visible to phase 2)
    i2h_gemm<<<dim3(T_STEPS / 4), dim3(1024), I2H_LDS_BYTES, stream>>>(
        x, W_ih, out);

    // phase 2: recurrence
    esn_persistent<<<dim3(NGROUPS * 64), dim3(NTHR), LDS_BYTES, stream>>>(
        lengths, W_hh, out, h_buf, flags);
}

// Round 5
// 3822.957 us; speedup vs baseline: 8.6720x; 1.6154x over previous
//
#include <hip/hip_runtime.h>
#include <math.h>

// ESN recurrence, round 8: cut coherent-fabric traffic 4x.
// r7 post-mortem: step = 14.3k cyc but VALU only ~2.3k; bank conflicts
// negligible; FETCH fixed. Remaining stall ~= IF$ bandwidth: each of 256
// blocks re-reads its group's h slice with device-scope loads (bypass L2)
// = 256 x BTILE x 4KB = 16 MB/step, 64x redundant -> ~2.7 TB/s observed.
// r8: traffic scales with BTILE -> reshape 4 groups x 64 htiles into
// 16 groups x 16 htiles (BTILE=4, HTILE=64). Each block: 64 H-rows x
// 4 batches, reads 16KB/step -> 4 MB/step total (4x cut). Same grid
// (256 blocks), same FMA/thread (512), same wreg 128 floats (no batch
// redundancy at 4Hx4B covering all 4 batches). Group barrier 64->16
// flags. Bank analysis redone: k-loop rotation (kk+kidx)&7 -> 4 distinct
// 16B slots per 128B (free); part[32][257] writes (kidx+4*th_i+i)%32 ->
// 2-way; reduce reads 2-way. LDS padded to 84KB -> 1 block/CU. Keeps
// r7-proven: i2h precompute into out, waves_per_eu(2,2) reg pin,
// __syncthreads + s_waitcnt(0) barrier protocol.

#define T_STEPS 1000
#define NB      64
#define NI      80
#define NH      1024
#define NCH     32               // K chunks
#define CH      32               // floats per chunk (K = 1024 exact)
#define LSTR    1028             // hx row stride (1024 + 4 pad floats)
#define PSTR    257              // part column stride
#define NGROUPS 16
#define BTILE   4                // batch rows per group
#define HTILE   64               // H rows per block
#define NTHR    512
#define HX_FLOATS   (BTILE * LSTR)               // 4112
#define PART_FLOATS (NCH * PSTR)                 // 8224
#define LDS_BYTES   86016        // 84 KB used-region pad -> 1 block/CU
#define I2H_LDS_BYTES (4 * NB * NI * 4)          // 81,920 B

typedef unsigned long long ull;

// ---------- phase 1: out[t,b,h] = sum_i x[t,b,i] * W_ih[h,i] ----------
__global__ __launch_bounds__(1024, 4) void i2h_gemm(
    const float* __restrict__ x,      // [T,B,I]
    const float* __restrict__ W_ih,   // [H,I]
    float* __restrict__ out)          // [T,B,H]
{
    extern __shared__ float xs[];     // [4][NB][NI] = 20480 floats
    const int tid = threadIdx.x;
    const int t0  = blockIdx.x * 4;

    {
        const float4* src = (const float4*)(x + (size_t)t0 * NB * NI);
        float4* dst = (float4*)xs;
        #pragma unroll
        for (int r = 0; r < 5; ++r)
            dst[tid + r * 1024] = src[tid + r * 1024];
    }
    float4 w[20];
    {
        const float4* wr = (const float4*)(W_ih + (size_t)tid * NI);
        #pragma unroll
        for (int k = 0; k < 20; ++k) w[k] = wr[k];
    }
    __syncthreads();

    for (int tq = 0; tq < 4; ++tq) {
        for (int jb = 0; jb < 16; ++jb) {
            const float* xb = xs + (size_t)(tq * NB + jb * 4) * NI;
            float a0 = 0.f, a1 = 0.f, a2 = 0.f, a3 = 0.f;
            #pragma unroll
            for (int k = 0; k < 20; ++k) {
                const float4 wv = w[k];
                float4 xv;
                xv = *(const float4*)(xb + k * 4);
                a0 = fmaf(wv.x, xv.x, fmaf(wv.y, xv.y,
                     fmaf(wv.z, xv.z, fmaf(wv.w, xv.w, a0))));
                xv = *(const float4*)(xb + NI + k * 4);
                a1 = fmaf(wv.x, xv.x, fmaf(wv.y, xv.y,
                     fmaf(wv.z, xv.z, fmaf(wv.w, xv.w, a1))));
                xv = *(const float4*)(xb + 2 * NI + k * 4);
                a2 = fmaf(wv.x, xv.x, fmaf(wv.y, xv.y,
                     fmaf(wv.z, xv.z, fmaf(wv.w, xv.w, a2))));
                xv = *(const float4*)(xb + 3 * NI + k * 4);
                a3 = fmaf(wv.x, xv.x, fmaf(wv.y, xv.y,
                     fmaf(wv.z, xv.z, fmaf(wv.w, xv.w, a3))));
            }
            float* ob = out + ((size_t)(t0 + tq) * NB + jb * 4) * NH + tid;
            ob[0]      = a0;
            ob[NH]     = a1;
            ob[2 * NH] = a2;
            ob[3 * NH] = a3;
        }
    }
}

// ---------- phase 2: persistent recurrence ----------
__attribute__((amdgpu_waves_per_eu(2, 2)))
__global__ void __launch_bounds__(NTHR) esn_persistent(
    const int*   __restrict__ lengths,  // [B] descending
    const float* __restrict__ W_hh,     // [H,H]
    float* __restrict__ out,            // [T,B,H], holds i2h on entry
    float*       h_buf,                 // ws: [2][B][H], zero-inited
    unsigned*    flags)                 // ws: [NGROUPS*16], zero-inited
{
    extern __shared__ float lds[];
    float* hx   = lds;                  // [BTILE][LSTR], plain layout
    float* part = lds + HX_FLOATS;      // [NCH][PSTR] column-major partials

    const int tid   = threadIdx.x;
    const int bid   = blockIdx.x;
    const int g     = bid & 15;         // 0..15 batch group (4 rows)
    const int htile = bid >> 4;         // 0..15 H tile (64 rows)
    const int hi0   = htile * HTILE;
    const int gb0   = g * BTILE;

    const int kidx = tid >> 4;          // 0..31 K-chunk
    const int th_i = tid & 15;          // H sub-tile (4 rows each)

    const int max_len = lengths[gb0];   // block-uniform (descending sort)
    unsigned* gflags = flags + g * 16;

    // ---- reader-thread (tid<256) precompute ----
    int lenr = 0, brow_r = 0, hrow_r = 0, hp_addr = 0;
    if (tid < 256) {
        const int b_local = tid >> 6;   // 0..3
        const int h_local = tid & 63;   // 0..63
        brow_r = gb0 + b_local;
        hrow_r = hi0 + h_local;
        lenr   = lengths[brow_r];
        hp_addr = b_local * LSTR + hrow_r;
    }

    // ---- rotated chunk offsets: 4 in-wave kidx -> 4 distinct 16B slots ----
    int off[8];
    #pragma unroll
    for (int kk = 0; kk < 8; ++kk)
        off[kk] = (kidx * 8 + ((kk + kidx) & 7)) * 4;

    // ---- W fragment -> VGPRs: rows hi0+4*th_i+i, rotated f4 columns ----
    float4 wreg[4][8];                  // 128 floats
    #pragma unroll
    for (int i = 0; i < 4; ++i) {
        const float* wr = W_hh + (size_t)(hi0 + th_i * 4 + i) * NH;
        #pragma unroll
        for (int kk = 0; kk < 8; ++kk)
            wreg[i][kk] = *(const float4*)(wr + off[kk]);
    }

    // ---- i2h prefetch (step 0) ----
    float i2h_c = 0.f;
    if (tid < 256 && max_len > 0)
        i2h_c = out[(size_t)brow_r * NH + hrow_r];

    for (int t = 0; t < max_len; ++t) {
        const float* h_cur = h_buf + (size_t)(t & 1) * (NB * NH);
        float*       h_nxt = h_buf + (size_t)((t + 1) & 1) * (NB * NH);

        // ---- stage h: 4 rows x 4KB = 2048 ull; 4 coherent loads/thread ----
        {
            const ull* h8 = (const ull*)(h_cur + (size_t)gb0 * NH);
            ull vb[4];
            #pragma unroll
            for (int it = 0; it < 4; ++it)
                vb[it] = __hip_atomic_load(h8 + (tid + it * NTHR),
                           __ATOMIC_RELAXED, __HIP_MEMORY_SCOPE_AGENT);
            #pragma unroll
            for (int it = 0; it < 4; ++it) {
                const int j = tid + it * NTHR;
                *(ull*)(&hx[(j >> 9) * LSTR + (j & 511) * 2]) = vb[it];
            }
        }
        __syncthreads();

        // ---- 4H x 4B micro-tile over this thread's 32-col K-chunk ----
        float acc[4][4];
        #pragma unroll
        for (int i = 0; i < 4; ++i)
            #pragma unroll
            for (int j = 0; j < 4; ++j) acc[i][j] = 0.f;

        #pragma unroll
        for (int j = 0; j < 4; ++j) {
            const float* hb = hx + (size_t)j * LSTR;
            #pragma unroll
            for (int kk = 0; kk < 8; ++kk) {
                const float4 hv = *(const float4*)(hb + off[kk]);
                #pragma unroll
                for (int i = 0; i < 4; ++i) {
                    acc[i][j] = fmaf(wreg[i][kk].x, hv.x,
                                fmaf(wreg[i][kk].y, hv.y,
                                fmaf(wreg[i][kk].z, hv.z,
                                fmaf(wreg[i][kk].w, hv.w, acc[i][j]))));
                }
            }
        }

        // ---- publish partials: part[kidx][j*64 + th_i*4 + i], 2-way banks ----
        #pragma unroll
        for (int i = 0; i < 4; ++i)
            #pragma unroll
            for (int j = 0; j < 4; ++j)
                part[kidx * PSTR + j * 64 + th_i * 4 + i] = acc[i][j];
        __syncthreads();

        // ---- reduce 32 partials (banks = c + tid mod 32: 2-way, free) ----
        float y = 0.f;
        if (tid < 256) {
            float s0 = 0.f, s1 = 0.f, s2 = 0.f, s3 = 0.f;
            #pragma unroll
            for (int c = 0; c < NCH; c += 4) {
                s0 += part[(c + 0) * PSTR + tid];
                s1 += part[(c + 1) * PSTR + tid];
                s2 += part[(c + 2) * PSTR + tid];
                s3 += part[(c + 3) * PSTR + tid];
            }
            const float accv = ((s0 + s1) + (s2 + s3)) + i2h_c;
            const float hp = hx[hp_addr];
            float hn;
            if (t < lenr) { hn = 0.5f * hp + 0.5f * tanhf(accv); y = hn; }
            else          { hn = hp; /* y stays 0 */ }
            __hip_atomic_store(&h_nxt[(size_t)brow_r * NH + hrow_r], hn,
                               __ATOMIC_RELAXED, __HIP_MEMORY_SCOPE_AGENT);
        }

        // ---- group barrier (proven): drain, flag, overlap, poll ----
        __builtin_amdgcn_s_waitcnt(0);   // this wave's stores complete at LLC
        __syncthreads();                 // => all waves' stores complete
        if (tid == 0)
            __hip_atomic_store(&gflags[htile], (unsigned)(t + 1),
                               __ATOMIC_RELAXED, __HIP_MEMORY_SCOPE_AGENT);
        if (tid < 256) {                 // overlap with the poll
            out[((size_t)t * NB + brow_r) * NH + hrow_r] = y;
            if (t + 1 < max_len)
                i2h_c = out[((size_t)(t + 1) * NB + brow_r) * NH + hrow_r];
        }
        if (tid < 16) {
            while (__hip_atomic_load(&gflags[tid],
                     __ATOMIC_RELAXED, __HIP_MEMORY_SCOPE_AGENT)
                   < (unsigned)(t + 1))
                __builtin_amdgcn_s_sleep(1);
        }
        __syncthreads();
    }

    // ---- tail: whole group past its max length -> zero outputs ----
    const float4 z4 = {0.f, 0.f, 0.f, 0.f};
    for (int p = tid; p < (T_STEPS - max_len) * 64; p += NTHR) {
        const int t  = max_len + (p >> 6);
        const int o  = p & 63;               // 4 b x 16 f4
        const int b  = o >> 4;
        const int c4 = o & 15;
        *(float4*)(out + ((size_t)t * NB + gb0 + b) * NH + hi0 + c4 * 4) = z4;
    }
}

extern "C" void kernel_launch(void* const* d_in, const int* in_sizes, int n_in,
                              void* d_out, int out_size, void* d_ws, size_t ws_size,
                              hipStream_t stream) {
    const float* x       = (const float*)d_in[0];
    const int*   lengths = (const int*)  d_in[1];
    const float* W_ih    = (const float*)d_in[2];
    const float* W_hh    = (const float*)d_in[3];
    float*       out     = (float*)d_out;

    float*    h_buf = (float*)d_ws;                                   // 512 KB
    unsigned* flags = (unsigned*)((char*)d_ws + 2 * NB * NH * sizeof(float));

    hipMemsetAsync(d_ws, 0,
                   2 * NB * NH * sizeof(float)
                   + NGROUPS * 16 * sizeof(unsigned),
                   stream);

    hipFuncSetAttribute((const void*)i2h_gemm,
                        hipFuncAttributeMaxDynamicSharedMemorySize, I2H_LDS_BYTES);
    hipFuncSetAttribute((const void*)esn_persistent,
                        hipFuncAttributeMaxDynamicSharedMemorySize, LDS_BYTES);

    // phase 1: i2h into out (stream-ordered; visible to phase 2)
    i2h_gemm<<<dim3(T_STEPS / 4), dim3(1024), I2H_LDS_BYTES, stream>>>(
        x, W_ih, out);

    // phase 2: recurrence
    esn_persistent<<<dim3(NGROUPS * 16), dim3(NTHR), LDS_BYTES, stream>>>(
        lengths, W_hh, out, h_buf, flags);
}